// Round 3
// baseline (5848.619 us; speedup 1.0000x reference)
//
#include <hip/hip_runtime.h>
#include <hip/hip_bf16.h>
#include <math.h>

// Seq2seq GRU (PyTorch gate order r,z,n), H=1024, L=2, S=T=512, V=32000.
//   1. gather_embed: enc_x[512][1024], dec_x[512][1024] (teacher-forced, BOS=0)
//   2. gru_persist:  persistent kernel, 256 WGs x 256 thr, 1 small WG per CU
//      (plain launch; 8.3KB LDS / ~150 VGPR so residency is never resource-capped).
//      WG w owns j = {4w..4w+3}; its 24 weight rows live in registers.
//      Cross-WG sync: tagged u64 {tag=pass+1 | f32 bits}, relaxed agent-scope
//      atomics. ALL SPINS ARE BOUNDED: after 100k poll iters (~30ms >> any legit
//      wait) the WG fills NaN and proceeds -> bench FAILS with absmax=nan instead
//      of hanging (diagnostic channel).
//   3. gemm_out: C[512][32000] = D1 @ out_W^T + out_b (tiled SIMT f32)
//   4. log_softmax_inplace on d_out.

#define HID 1024
#define NSTEP 512
#define VOCAB 32000
#define SPIN_LIMIT 100000
typedef unsigned long long u64;

__device__ __forceinline__ u64 pack_hv(float v, unsigned tag) {
    return ((u64)tag << 32) | (u64)__float_as_uint(v);
}

// 256 threads poll a 1024-entry tagged row until every tag == want; payloads are
// staged into dst (LDS). 4 pairs/thread. Bounded: on give-up, fill NaN (uniform
// decision across the WG -- all threads share the same iteration count).
__device__ __forceinline__ void stage_tagged(const u64* __restrict__ row, unsigned want,
                                             float* dst, int tid) {
    bool have = false;
    int iter = 0;
    for (;;) {
        if (!have) {
            u64 v[4];
            bool ok = true;
#pragma unroll
            for (int q = 0; q < 4; q++) {
                v[q] = __hip_atomic_load((u64*)(row + tid * 4 + q),
                                         __ATOMIC_RELAXED, __HIP_MEMORY_SCOPE_AGENT);
                ok = ok && ((unsigned)(v[q] >> 32) == want);
            }
            if (ok) {
#pragma unroll
                for (int q = 0; q < 4; q++)
                    dst[tid * 4 + q] = __uint_as_float((unsigned)(v[q] & 0xffffffffu));
                have = true;
            } else if (++iter >= SPIN_LIMIT) {
#pragma unroll
                for (int q = 0; q < 4; q++) dst[tid * 4 + q] = __uint_as_float(0x7fc00000u);
                have = true;  // give up -> NaN poisons output -> absmax=nan signal
            } else {
                __builtin_amdgcn_s_sleep(2);
            }
        }
        if (__syncthreads_count(!have) == 0) return;
    }
}

// ---------------------------------------------------------------- embeddings
__global__ __launch_bounds__(256) void gather_embed(
    const int* __restrict__ src_tok, const int* __restrict__ tgt_tok,
    const float* __restrict__ src_emb, const float* __restrict__ tgt_emb,
    float* __restrict__ enc_x, float* __restrict__ dec_x) {
    int b = blockIdx.x, tid = threadIdx.x;
    int tok;
    const float* src;
    float* dst;
    if (b < 512) {
        tok = src_tok[b];
        src = src_emb;
        dst = enc_x + (size_t)b * HID;
    } else {
        int t = b - 512;
        tok = (t == 0) ? 0 : tgt_tok[t - 1];  // BOS = 0
        src = tgt_emb;
        dst = dec_x + (size_t)t * HID;
    }
    float4 v = *(const float4*)(src + (size_t)tok * HID + tid * 4);
    *(float4*)(dst + tid * 4) = v;
}

// ---------------------------------------------------------------- recurrence
// 256 WGs x 256 threads. Wave w owns rows m=6w..6w+5 of the 24 per-WG rows;
// m<12 -> Wih row (g=m>>2, jj=m&3) dotted with x; m>=12 -> Whh row dotted with h.
// Lane l holds W[row][q*64+l], q<16 (96 VGPR of weights).
__global__ __launch_bounds__(256, 1) void gru_persist(
    const float* __restrict__ enc_x, const float* __restrict__ dec_x,
    const float* __restrict__ eWih, const float* __restrict__ eWhh,
    const float* __restrict__ eBih, const float* __restrict__ eBhh,
    const float* __restrict__ dWih, const float* __restrict__ dWhh,
    const float* __restrict__ dBih, const float* __restrict__ dBhh,
    u64* H0, u64* H1, u64* D0, u64* D1, float* __restrict__ D1f) {
    const int tid = threadIdx.x;
    const int wave = tid >> 6, lane = tid & 63;
    const int j0 = blockIdx.x * 4;

    __shared__ __align__(16) float x_lds[HID];
    __shared__ __align__(16) float h_lds[HID];
    __shared__ float dots[24];
    __shared__ float sbias[24];

    float wreg[6][16];

#pragma unroll 1
    for (int pass = 0; pass < 4; ++pass) {
        const int layer = pass & 1;
        const bool dec = pass >= 2;
        const float* Wih = (dec ? dWih : eWih) + (size_t)layer * 3 * HID * HID;
        const float* Whh = (dec ? dWhh : eWhh) + (size_t)layer * 3 * HID * HID;
        const float* bih = (dec ? dBih : eBih) + (size_t)layer * 3 * HID;
        const float* bhh = (dec ? dBhh : eBhh) + (size_t)layer * 3 * HID;
        u64* htr = (pass == 0) ? H0 : (pass == 1) ? H1 : (pass == 2) ? D0 : D1;
        const unsigned tag = (unsigned)pass + 1u;

        // ---- stage this pass's 24 weight rows into registers (coalesced)
#pragma unroll
        for (int r = 0; r < 6; r++) {
            int m = wave * 6 + r;
            int mm = (m < 12) ? m : m - 12;
            const float* rowp = ((m < 12) ? Wih : Whh) +
                                (size_t)((mm >> 2) * HID + j0 + (mm & 3)) * HID;
#pragma unroll
            for (int q = 0; q < 16; q++) wreg[r][q] = rowp[q * 64 + lane];
        }
        if (tid < 24) {
            int m = tid, mm = (m < 12) ? m : m - 12;
            sbias[m] = ((m < 12) ? bih : bhh)[(mm >> 2) * HID + j0 + (mm & 3)];
        }
        __syncthreads();

        for (int t = 0; t < NSTEP; ++t) {
            // ---- stage x_t
            if (pass == 0 || pass == 2) {
                const float* xr = (pass == 0 ? enc_x : dec_x) + (size_t)t * HID;
                *(float4*)&x_lds[tid * 4] = *(const float4*)&xr[tid * 4];
            } else {
                const u64* xr = (pass == 1 ? H0 : D0) + (size_t)t * HID;
                stage_tagged(xr, pass == 1 ? 1u : 3u, x_lds, tid);
            }
            // ---- stage h_{t-1}
            if (t > 0) {
                stage_tagged(htr + (size_t)(t - 1) * HID, tag, h_lds, tid);
            } else if (pass == 2) {
                stage_tagged(H0 + (size_t)(NSTEP - 1) * HID, 1u, h_lds, tid);
            } else if (pass == 3) {
                stage_tagged(H1 + (size_t)(NSTEP - 1) * HID, 2u, h_lds, tid);
            } else {
                *(float4*)&h_lds[tid * 4] = make_float4(0.f, 0.f, 0.f, 0.f);
            }
            __syncthreads();

            // ---- 24 dot products: per-lane 16 LDS reads (stride-1 across lanes)
            const float* vsrc = (wave < 2) ? x_lds : h_lds;
            float v[16];
#pragma unroll
            for (int q = 0; q < 16; q++) v[q] = vsrc[q * 64 + lane];
            float part[6];
#pragma unroll
            for (int r = 0; r < 6; r++) {
                float a = 0.f;
#pragma unroll
                for (int q = 0; q < 16; q++) a = fmaf(wreg[r][q], v[q], a);
                part[r] = a;
            }
#pragma unroll
            for (int off = 1; off < 64; off <<= 1) {
#pragma unroll
                for (int r = 0; r < 6; r++) part[r] += __shfl_xor(part[r], off);
            }
            if (lane == 0) {
#pragma unroll
                for (int r = 0; r < 6; r++) dots[wave * 6 + r] = part[r];
            }
            __syncthreads();

            // ---- gates + tagged publish (4 lanes, one per owned j)
            if (tid < 4) {
                const int jj = tid;
                float ir = dots[jj] + sbias[jj];
                float iz = dots[4 + jj] + sbias[4 + jj];
                float in_ = dots[8 + jj] + sbias[8 + jj];
                float hr = dots[12 + jj] + sbias[12 + jj];
                float hz = dots[16 + jj] + sbias[16 + jj];
                float hn = dots[20 + jj] + sbias[20 + jj];
                float rg = 1.f / (1.f + __expf(-(ir + hr)));
                float zg = 1.f / (1.f + __expf(-(iz + hz)));
                float na = in_ + rg * hn;
                float ng = 2.f / (1.f + __expf(-2.f * na)) - 1.f;  // tanh
                float hprev = h_lds[j0 + jj];
                float hnew = (1.f - zg) * ng + zg * hprev;
                __hip_atomic_store((u64*)(htr + (size_t)t * HID + j0 + jj),
                                   pack_hv(hnew, tag),
                                   __ATOMIC_RELAXED, __HIP_MEMORY_SCOPE_AGENT);
                if (pass == 3) D1f[(size_t)t * HID + j0 + jj] = hnew;
            }
            __syncthreads();  // protect x_lds/h_lds/dots/sbias for next iter/pass
        }
    }
}

// ---------------------------------------------------------------- output GEMM
// C[i][v] = sum_k A[i][k]*B[v][k] + bias[v].  A:[512][1024]  B:[32000][1024]
__global__ __launch_bounds__(256) void gemm_out(
    const float* __restrict__ A, const float* __restrict__ B,
    const float* __restrict__ bias, float* __restrict__ C) {
    const int tid = threadIdx.x;
    const int bi = blockIdx.x;  // 8
    const int bv = blockIdx.y;  // 250
    const int i0 = bi * 64, v0 = bv * 128;
    __shared__ __align__(16) float As[32 * 68];
    __shared__ __align__(16) float Bs[32 * 132];
    const int tr = tid >> 4, tc = tid & 15;
    float c[4][8] = {};

    for (int kk = 0; kk < HID; kk += 32) {
#pragma unroll
        for (int q = 0; q < 2; q++) {
            int id = tid * 2 + q;  // 0..511
            int r = id >> 3, kq = id & 7;
            float4 a = *(const float4*)&A[(size_t)(i0 + r) * HID + kk + kq * 4];
            As[(kq * 4 + 0) * 68 + r] = a.x;
            As[(kq * 4 + 1) * 68 + r] = a.y;
            As[(kq * 4 + 2) * 68 + r] = a.z;
            As[(kq * 4 + 3) * 68 + r] = a.w;
        }
#pragma unroll
        for (int q = 0; q < 4; q++) {
            int id = tid * 4 + q;  // 0..1023
            int vr = id >> 3, kq = id & 7;
            float4 b = *(const float4*)&B[(size_t)(v0 + vr) * HID + kk + kq * 4];
            Bs[(kq * 4 + 0) * 132 + vr] = b.x;
            Bs[(kq * 4 + 1) * 132 + vr] = b.y;
            Bs[(kq * 4 + 2) * 132 + vr] = b.z;
            Bs[(kq * 4 + 3) * 132 + vr] = b.w;
        }
        __syncthreads();
#pragma unroll
        for (int k = 0; k < 32; k++) {
            float4 a4 = *(const float4*)&As[k * 68 + tr * 4];
            float4 b0 = *(const float4*)&Bs[k * 132 + tc * 8];
            float4 b1 = *(const float4*)&Bs[k * 132 + tc * 8 + 4];
            float av[4] = {a4.x, a4.y, a4.z, a4.w};
            float bvv[8] = {b0.x, b0.y, b0.z, b0.w, b1.x, b1.y, b1.z, b1.w};
#pragma unroll
            for (int u = 0; u < 4; u++)
#pragma unroll
                for (int w = 0; w < 8; w++) c[u][w] += av[u] * bvv[w];
        }
        __syncthreads();
    }
    float4 bb0 = *(const float4*)&bias[v0 + tc * 8];
    float4 bb1 = *(const float4*)&bias[v0 + tc * 8 + 4];
#pragma unroll
    for (int u = 0; u < 4; u++) {
        int i = i0 + tr * 4 + u;
        float4 o0 = {c[u][0] + bb0.x, c[u][1] + bb0.y, c[u][2] + bb0.z, c[u][3] + bb0.w};
        float4 o1 = {c[u][4] + bb1.x, c[u][5] + bb1.y, c[u][6] + bb1.z, c[u][7] + bb1.w};
        *(float4*)&C[(size_t)i * VOCAB + v0 + tc * 8] = o0;
        *(float4*)&C[(size_t)i * VOCAB + v0 + tc * 8 + 4] = o1;
    }
}

// ---------------------------------------------------------------- log-softmax
__global__ __launch_bounds__(256) void log_softmax_inplace(float* __restrict__ C) {
    const int row = blockIdx.x;
    const int tid = threadIdx.x;
    float* p = C + (size_t)row * VOCAB;
    float m = -3.4e38f, s = 0.f;
    for (int idx = tid; idx < VOCAB / 4; idx += 256) {
        float4 x = ((const float4*)p)[idx];
        float xv[4] = {x.x, x.y, x.z, x.w};
#pragma unroll
        for (int u = 0; u < 4; u++) {
            float nm = fmaxf(m, xv[u]);
            s = s * __expf(m - nm) + __expf(xv[u] - nm);
            m = nm;
        }
    }
#pragma unroll
    for (int off = 1; off < 64; off <<= 1) {
        float om = __shfl_xor(m, off);
        float os = __shfl_xor(s, off);
        float nm = fmaxf(m, om);
        s = s * __expf(m - nm) + os * __expf(om - nm);
        m = nm;
    }
    __shared__ float sm[4], ss[4], sL;
    int wv = tid >> 6;
    if ((tid & 63) == 0) { sm[wv] = m; ss[wv] = s; }
    __syncthreads();
    if (tid == 0) {
        float M = sm[0], S = ss[0];
        for (int w = 1; w < 4; w++) {
            float nm = fmaxf(M, sm[w]);
            S = S * __expf(M - nm) + ss[w] * __expf(sm[w] - nm);
            M = nm;
        }
        sL = M + logf(S);
    }
    __syncthreads();
    float L = sL;
    for (int idx = tid; idx < VOCAB / 4; idx += 256) {
        float4 x = ((const float4*)p)[idx];
        x.x -= L; x.y -= L; x.z -= L; x.w -= L;
        ((float4*)p)[idx] = x;
    }
}

// ---------------------------------------------------------------- launcher
extern "C" void kernel_launch(void* const* d_in, const int* in_sizes, int n_in,
                              void* d_out, int out_size, void* d_ws, size_t ws_size,
                              hipStream_t stream) {
    const int* src_tok = (const int*)d_in[0];
    const int* tgt_tok = (const int*)d_in[1];
    const float* src_emb = (const float*)d_in[2];
    const float* tgt_emb = (const float*)d_in[3];
    const float* eWih = (const float*)d_in[4];
    const float* eWhh = (const float*)d_in[5];
    const float* eBih = (const float*)d_in[6];
    const float* eBhh = (const float*)d_in[7];
    const float* dWih = (const float*)d_in[8];
    const float* dWhh = (const float*)d_in[9];
    const float* dBih = (const float*)d_in[10];
    const float* dBhh = (const float*)d_in[11];
    const float* out_W = (const float*)d_in[12];
    const float* out_b = (const float*)d_in[13];
    float* out = (float*)d_out;

    char* ws = (char*)d_ws;
    // layout: enc_x 2MB | dec_x 2MB | H0 4MB | H1 4MB | D0 4MB | D1 4MB | D1f 2MB
    float* enc_x = (float*)(ws);
    float* dec_x = (float*)(ws + (2ull << 20));
    u64* H0 = (u64*)(ws + (4ull << 20));
    u64* H1 = (u64*)(ws + (8ull << 20));
    u64* D0 = (u64*)(ws + (12ull << 20));
    u64* D1 = (u64*)(ws + (16ull << 20));
    float* D1f = (float*)(ws + (20ull << 20));

    // Clear sync tags every launch: stale/poisoned tags must never match (tags 1..4).
    hipMemsetAsync(ws + (4ull << 20), 0, 16ull << 20, stream);

    gather_embed<<<1024, 256, 0, stream>>>(src_tok, tgt_tok, src_emb, tgt_emb, enc_x, dec_x);
    gru_persist<<<256, 256, 0, stream>>>(enc_x, dec_x, eWih, eWhh, eBih, eBhh,
                                         dWih, dWhh, dBih, dBhh, H0, H1, D0, D1, D1f);
    gemm_out<<<dim3(8, 250), 256, 0, stream>>>(D1f, out_W, out_b, out);
    log_softmax_inplace<<<512, 256, 0, stream>>>(out);
}

// Round 4
// 3732.688 us; speedup vs baseline: 1.5669x; 1.5669x over previous
//
#include <hip/hip_runtime.h>
#include <hip/hip_bf16.h>
#include <math.h>

// Seq2seq GRU (PyTorch gate order r,z,n), H=1024, L=2, S=T=512, V=32000.
// Round 4: PIPELINED persistent recurrence.
//   - 256 WGs x 256 thr. role = wg>>7 (0: layer0, 1: layer1), each WG owns 8
//     elements j = [8*(wg&127), +8). Two phases: enc, dec. L0 and L1 run
//     CONCURRENTLY (L1 lags L0 by one step) -> critical path ~1026 hops
//     instead of 2048.
//   - 48 weight rows per WG live in registers (12 rows/wave, 192 VGPR).
//     Waves 0-1 dot Wih rows with x_t; waves 2-3 dot Whh rows with h_{t-1}.
//   - No LDS staging: each lane polls its 16 tagged u64 pairs {tag|f32}
//     (relaxed agent-scope) directly into registers. Gate lanes (tid<8) carry
//     their own element's h_prev in a register across steps AND phases.
//   - All spins bounded -> NaN fill (bench fails visibly instead of hanging).
// Then: gemm_out (tiled SIMT f32) + log_softmax_inplace on d_out.

#define HID 1024
#define NSTEP 512
#define VOCAB 32000
#define SPIN_LIMIT 50000
typedef unsigned long long u64;

__device__ __forceinline__ u64 pack_hv(float v, unsigned tag) {
    return ((u64)tag << 32) | (u64)__float_as_uint(v);
}

// Per-lane: poll 16 tagged pairs row[q*64+lane] until all tags == want; extract
// f32 payloads into v[16]. Bounded: on give-up fill NaN (diagnostic channel).
__device__ __forceinline__ void poll16(const u64* __restrict__ row, unsigned want,
                                       float* v, int lane) {
    u64 p[16];
    int iter = 0;
    for (;;) {
        bool ok = true;
#pragma unroll
        for (int q = 0; q < 16; ++q) {
            p[q] = __hip_atomic_load((u64*)(row + q * 64 + lane),
                                     __ATOMIC_RELAXED, __HIP_MEMORY_SCOPE_AGENT);
            ok = ok && ((unsigned)(p[q] >> 32) == want);
        }
        if (ok) break;
        if (++iter >= SPIN_LIMIT) {
#pragma unroll
            for (int q = 0; q < 16; ++q) v[q] = __uint_as_float(0x7fc00000u);
            return;
        }
        __builtin_amdgcn_s_sleep(1);
    }
#pragma unroll
    for (int q = 0; q < 16; ++q)
        v[q] = __uint_as_float((unsigned)(p[q] & 0xffffffffu));
}

// ---------------------------------------------------------------- embeddings
__global__ __launch_bounds__(256) void gather_embed(
    const int* __restrict__ src_tok, const int* __restrict__ tgt_tok,
    const float* __restrict__ src_emb, const float* __restrict__ tgt_emb,
    float* __restrict__ enc_x, float* __restrict__ dec_x) {
    int b = blockIdx.x, tid = threadIdx.x;
    int tok;
    const float* src;
    float* dst;
    if (b < 512) {
        tok = src_tok[b];
        src = src_emb;
        dst = enc_x + (size_t)b * HID;
    } else {
        int t = b - 512;
        tok = (t == 0) ? 0 : tgt_tok[t - 1];  // BOS = 0
        src = tgt_emb;
        dst = dec_x + (size_t)t * HID;
    }
    float4 v = *(const float4*)(src + (size_t)tok * HID + tid * 4);
    *(float4*)(dst + tid * 4) = v;
}

// ---------------------------------------------------------------- recurrence
// Row R = wave*12 + r of the 48 per-WG rows. R<24 -> Wih row (m=R), else Whh
// (m=R-24); m = g*8 + jj. Lane l holds W[row][q*64+l], q<16.
// dots[R] / sbias[R] layout: index = mat*24 + g*8 + jj.
__global__ __launch_bounds__(256, 1) void gru_persist(
    const float* __restrict__ enc_x, const float* __restrict__ dec_x,
    const float* __restrict__ eWih, const float* __restrict__ eWhh,
    const float* __restrict__ eBih, const float* __restrict__ eBhh,
    const float* __restrict__ dWih, const float* __restrict__ dWhh,
    const float* __restrict__ dBih, const float* __restrict__ dBhh,
    u64* H0, u64* H1, u64* D0, u64* D1, float* __restrict__ D1f) {
    const int tid = threadIdx.x;
    const int wave = tid >> 6, lane = tid & 63;
    const int role = blockIdx.x >> 7;       // 0 = layer0, 1 = layer1
    const int wl = blockIdx.x & 127;
    const int j0 = wl * 8;

    __shared__ float dots[48];
    __shared__ float sbias[48];

    float wreg[12][16];
    float hprev = 0.f;  // gate lanes (tid<8): own element's h, carried across phases

#pragma unroll 1
    for (int phase = 0; phase < 2; ++phase) {
        const bool dec = (phase == 1);
        const float* Wih = (dec ? dWih : eWih) + (size_t)role * 3 * HID * HID;
        const float* Whh = (dec ? dWhh : eWhh) + (size_t)role * 3 * HID * HID;
        const float* bih = (dec ? dBih : eBih) + (size_t)role * 3 * HID;
        const float* bhh = (dec ? dBhh : eBhh) + (size_t)role * 3 * HID;
        // own chain buffer + tag
        u64* hch = dec ? (role ? D1 : D0) : (role ? H1 : H0);
        const unsigned tagOut = dec ? (role ? 4u : 3u) : (role ? 2u : 1u);
        // x source (role1 reads the layer-0 chain live)
        const float* xf = dec ? dec_x : enc_x;           // role0
        const u64* xt = dec ? D0 : H0;                   // role1
        const unsigned tagX = dec ? 3u : 1u;
        // h init at t==0 (dec only; enc starts from zeros)
        const u64* hinit = role ? (H1 + (size_t)(NSTEP - 1) * HID)
                                : (H0 + (size_t)(NSTEP - 1) * HID);
        const unsigned tagInit = role ? 2u : 1u;

        // ---- stage 48 weight rows into registers (once per phase)
        __syncthreads();  // protect sbias/dots from previous phase's last step
#pragma unroll
        for (int r = 0; r < 12; ++r) {
            int R = wave * 12 + r;
            int m = (R < 24) ? R : R - 24;
            const float* base = ((R < 24) ? Wih : Whh) +
                                (size_t)((m >> 3) * HID + j0 + (m & 7)) * HID;
#pragma unroll
            for (int q = 0; q < 16; ++q) wreg[r][q] = base[q * 64 + lane];
        }
        if (tid < 48) {
            int m = (tid < 24) ? tid : tid - 24;
            sbias[tid] = ((tid < 24) ? bih : bhh)[(m >> 3) * HID + j0 + (m & 7)];
        }
        __syncthreads();

#pragma unroll 1
        for (int t = 0; t < NSTEP; ++t) {
            // ---- operand into registers (per-wave: x for waves 0-1, h for 2-3)
            float v[16];
            if (wave < 2) {
                if (role == 0) {
                    const float* xr = xf + (size_t)t * HID;
#pragma unroll
                    for (int q = 0; q < 16; ++q) v[q] = xr[q * 64 + lane];
                } else {
                    poll16(xt + (size_t)t * HID, tagX, v, lane);
                }
            } else {
                if (t > 0) {
                    poll16(hch + (size_t)(t - 1) * HID, tagOut, v, lane);
                } else if (dec) {
                    poll16(hinit, tagInit, v, lane);
                } else {
#pragma unroll
                    for (int q = 0; q < 16; ++q) v[q] = 0.f;
                }
            }

            // ---- 12 dots per wave
            float part[12];
#pragma unroll
            for (int r = 0; r < 12; ++r) {
                float a = 0.f;
#pragma unroll
                for (int q = 0; q < 16; ++q) a = fmaf(wreg[r][q], v[q], a);
                part[r] = a;
            }
#pragma unroll
            for (int off = 1; off < 64; off <<= 1) {
#pragma unroll
                for (int r = 0; r < 12; ++r) part[r] += __shfl_xor(part[r], off);
            }
            if (lane == 0) {
#pragma unroll
                for (int r = 0; r < 12; ++r) dots[wave * 12 + r] = part[r];
            }
            __syncthreads();

            // ---- gates + tagged publish (8 lanes of wave 0)
            if (tid < 8) {
                const int jj = tid;
                float ir = dots[jj] + sbias[jj];
                float iz = dots[8 + jj] + sbias[8 + jj];
                float in_ = dots[16 + jj] + sbias[16 + jj];
                float hr = dots[24 + jj] + sbias[24 + jj];
                float hz = dots[32 + jj] + sbias[32 + jj];
                float hn = dots[40 + jj] + sbias[40 + jj];
                float rg = 1.f / (1.f + __expf(-(ir + hr)));
                float zg = 1.f / (1.f + __expf(-(iz + hz)));
                float na = in_ + rg * hn;
                float ng = 2.f / (1.f + __expf(-2.f * na)) - 1.f;  // tanh
                float hnew = (1.f - zg) * ng + zg * hprev;
                hprev = hnew;
                __hip_atomic_store((u64*)(hch + (size_t)t * HID + j0 + jj),
                                   pack_hv(hnew, tagOut),
                                   __ATOMIC_RELAXED, __HIP_MEMORY_SCOPE_AGENT);
                if (dec && role == 1) D1f[(size_t)t * HID + j0 + jj] = hnew;
            }
            __syncthreads();  // dots/sbias reuse guard
        }
    }
}

// ---------------------------------------------------------------- output GEMM
// C[i][v] = sum_k A[i][k]*B[v][k] + bias[v].  A:[512][1024]  B:[32000][1024]
__global__ __launch_bounds__(256) void gemm_out(
    const float* __restrict__ A, const float* __restrict__ B,
    const float* __restrict__ bias, float* __restrict__ C) {
    const int tid = threadIdx.x;
    const int bi = blockIdx.x;  // 8
    const int bv = blockIdx.y;  // 250
    const int i0 = bi * 64, v0 = bv * 128;
    __shared__ __align__(16) float As[32 * 68];
    __shared__ __align__(16) float Bs[32 * 132];
    const int tr = tid >> 4, tc = tid & 15;
    float c[4][8] = {};

    for (int kk = 0; kk < HID; kk += 32) {
#pragma unroll
        for (int q = 0; q < 2; q++) {
            int id = tid * 2 + q;  // 0..511
            int r = id >> 3, kq = id & 7;
            float4 a = *(const float4*)&A[(size_t)(i0 + r) * HID + kk + kq * 4];
            As[(kq * 4 + 0) * 68 + r] = a.x;
            As[(kq * 4 + 1) * 68 + r] = a.y;
            As[(kq * 4 + 2) * 68 + r] = a.z;
            As[(kq * 4 + 3) * 68 + r] = a.w;
        }
#pragma unroll
        for (int q = 0; q < 4; q++) {
            int id = tid * 4 + q;  // 0..1023
            int vr = id >> 3, kq = id & 7;
            float4 b = *(const float4*)&B[(size_t)(v0 + vr) * HID + kk + kq * 4];
            Bs[(kq * 4 + 0) * 132 + vr] = b.x;
            Bs[(kq * 4 + 1) * 132 + vr] = b.y;
            Bs[(kq * 4 + 2) * 132 + vr] = b.z;
            Bs[(kq * 4 + 3) * 132 + vr] = b.w;
        }
        __syncthreads();
#pragma unroll
        for (int k = 0; k < 32; k++) {
            float4 a4 = *(const float4*)&As[k * 68 + tr * 4];
            float4 b0 = *(const float4*)&Bs[k * 132 + tc * 8];
            float4 b1 = *(const float4*)&Bs[k * 132 + tc * 8 + 4];
            float av[4] = {a4.x, a4.y, a4.z, a4.w};
            float bvv[8] = {b0.x, b0.y, b0.z, b0.w, b1.x, b1.y, b1.z, b1.w};
#pragma unroll
            for (int u = 0; u < 4; u++)
#pragma unroll
                for (int w = 0; w < 8; w++) c[u][w] += av[u] * bvv[w];
        }
        __syncthreads();
    }
    float4 bb0 = *(const float4*)&bias[v0 + tc * 8];
    float4 bb1 = *(const float4*)&bias[v0 + tc * 8 + 4];
#pragma unroll
    for (int u = 0; u < 4; u++) {
        int i = i0 + tr * 4 + u;
        float4 o0 = {c[u][0] + bb0.x, c[u][1] + bb0.y, c[u][2] + bb0.z, c[u][3] + bb0.w};
        float4 o1 = {c[u][4] + bb1.x, c[u][5] + bb1.y, c[u][6] + bb1.z, c[u][7] + bb1.w};
        *(float4*)&C[(size_t)i * VOCAB + v0 + tc * 8] = o0;
        *(float4*)&C[(size_t)i * VOCAB + v0 + tc * 8 + 4] = o1;
    }
}

// ---------------------------------------------------------------- log-softmax
__global__ __launch_bounds__(256) void log_softmax_inplace(float* __restrict__ C) {
    const int row = blockIdx.x;
    const int tid = threadIdx.x;
    float* p = C + (size_t)row * VOCAB;
    float m = -3.4e38f, s = 0.f;
    for (int idx = tid; idx < VOCAB / 4; idx += 256) {
        float4 x = ((const float4*)p)[idx];
        float xv[4] = {x.x, x.y, x.z, x.w};
#pragma unroll
        for (int u = 0; u < 4; u++) {
            float nm = fmaxf(m, xv[u]);
            s = s * __expf(m - nm) + __expf(xv[u] - nm);
            m = nm;
        }
    }
#pragma unroll
    for (int off = 1; off < 64; off <<= 1) {
        float om = __shfl_xor(m, off);
        float os = __shfl_xor(s, off);
        float nm = fmaxf(m, om);
        s = s * __expf(m - nm) + os * __expf(om - nm);
        m = nm;
    }
    __shared__ float sm[4], ss[4], sL;
    int wv = tid >> 6;
    if ((tid & 63) == 0) { sm[wv] = m; ss[wv] = s; }
    __syncthreads();
    if (tid == 0) {
        float M = sm[0], S = ss[0];
        for (int w = 1; w < 4; w++) {
            float nm = fmaxf(M, sm[w]);
            S = S * __expf(M - nm) + ss[w] * __expf(sm[w] - nm);
            M = nm;
        }
        sL = M + logf(S);
    }
    __syncthreads();
    float L = sL;
    for (int idx = tid; idx < VOCAB / 4; idx += 256) {
        float4 x = ((const float4*)p)[idx];
        x.x -= L; x.y -= L; x.z -= L; x.w -= L;
        ((float4*)p)[idx] = x;
    }
}

// ---------------------------------------------------------------- launcher
extern "C" void kernel_launch(void* const* d_in, const int* in_sizes, int n_in,
                              void* d_out, int out_size, void* d_ws, size_t ws_size,
                              hipStream_t stream) {
    const int* src_tok = (const int*)d_in[0];
    const int* tgt_tok = (const int*)d_in[1];
    const float* src_emb = (const float*)d_in[2];
    const float* tgt_emb = (const float*)d_in[3];
    const float* eWih = (const float*)d_in[4];
    const float* eWhh = (const float*)d_in[5];
    const float* eBih = (const float*)d_in[6];
    const float* eBhh = (const float*)d_in[7];
    const float* dWih = (const float*)d_in[8];
    const float* dWhh = (const float*)d_in[9];
    const float* dBih = (const float*)d_in[10];
    const float* dBhh = (const float*)d_in[11];
    const float* out_W = (const float*)d_in[12];
    const float* out_b = (const float*)d_in[13];
    float* out = (float*)d_out;

    char* ws = (char*)d_ws;
    // layout: enc_x 2MB | dec_x 2MB | H0 4MB | H1 4MB | D0 4MB | D1 4MB | D1f 2MB
    float* enc_x = (float*)(ws);
    float* dec_x = (float*)(ws + (2ull << 20));
    u64* H0 = (u64*)(ws + (4ull << 20));
    u64* H1 = (u64*)(ws + (8ull << 20));
    u64* D0 = (u64*)(ws + (12ull << 20));
    u64* D1 = (u64*)(ws + (16ull << 20));
    float* D1f = (float*)(ws + (20ull << 20));

    // Clear sync tags every launch: stale/poisoned tags must never match (tags 1..4).
    hipMemsetAsync(ws + (4ull << 20), 0, 16ull << 20, stream);

    gather_embed<<<1024, 256, 0, stream>>>(src_tok, tgt_tok, src_emb, tgt_emb, enc_x, dec_x);
    gru_persist<<<256, 256, 0, stream>>>(enc_x, dec_x, eWih, eWhh, eBih, eBhh,
                                         dWih, dWhh, dBih, dBhh, H0, H1, D0, D1, D1f);
    gemm_out<<<dim3(8, 250), 256, 0, stream>>>(D1f, out_W, out_b, out);
    log_softmax_inplace<<<512, 256, 0, stream>>>(out);
}